// Round 1
// baseline (371.089 us; speedup 1.0000x reference)
//
#include <hip/hip_runtime.h>

#define DEV __device__ __forceinline__

typedef __bf16 bf16x8 __attribute__((ext_vector_type(8)));
typedef float f32x4 __attribute__((ext_vector_type(4)));

static constexpr int Tn = 2048;
static constexpr int Dn = 1024;
static constexpr int NHn = 32;
static constexpr int HDn = 32;
static constexpr int Mn = 2 * Tn;  // B*T = 4096

DEV unsigned short f2bf(float f) {
    unsigned int u = __builtin_bit_cast(unsigned int, f);
    u = u + 0x7FFFu + ((u >> 16) & 1u);
    return (unsigned short)(u >> 16);
}
DEV float bf2f(unsigned short h) {
    return __builtin_bit_cast(float, ((unsigned int)h) << 16);
}

// ---------------- cast fp32 -> bf16 (vectorized float4) ----------------
__global__ __launch_bounds__(256) void cast_f32_bf16(const float* __restrict__ src,
                                                     unsigned short* __restrict__ dst, int n4) {
    int i = blockIdx.x * 256 + threadIdx.x;
    if (i >= n4) return;
    float4 v = reinterpret_cast<const float4*>(src)[i];
    ushort4 o;
    o.x = f2bf(v.x); o.y = f2bf(v.y); o.z = f2bf(v.z); o.w = f2bf(v.w);
    reinterpret_cast<ushort4*>(dst)[i] = o;
}

// ---------------- bf16 MFMA GEMM:  C = A * B^T  (A: MxK, B: NxK, row-major) ----------------
// 64x64 block tile, 4 waves (2x2), each wave 32x32 via 2x2 MFMA 16x16x32 tiles, BK=32.
template <bool OUT_BF16>
__global__ __launch_bounds__(256) void gemm_bt(
    const unsigned short* __restrict__ A,
    const unsigned short* __restrict__ B0, const unsigned short* __restrict__ B1,
    const unsigned short* __restrict__ B2,
    void* __restrict__ C0, void* __restrict__ C1, void* __restrict__ C2,
    int M, int N, int K) {
    const int z = blockIdx.z;
    const unsigned short* Bm = (z == 0) ? B0 : ((z == 1) ? B1 : B2);
    void* Cm = (z == 0) ? C0 : ((z == 1) ? C1 : C2);
    const int m0 = blockIdx.x * 64, n0 = blockIdx.y * 64;
    const int tid = threadIdx.x;
    const int w = tid >> 6, l = tid & 63;
    const int wm = w & 1, wn = w >> 1;
    const int lm = l & 15, quad = l >> 4;

    __shared__ __align__(16) unsigned short As[64][40];  // +8 pad keeps 16B align, breaks conflicts
    __shared__ __align__(16) unsigned short Bs[64][40];

    f32x4 acc[2][2] = {};

    const int srow = tid >> 2, sseg = tid & 3;
    const unsigned short* gA = A + (long)(m0 + srow) * K + sseg * 8;
    const unsigned short* gB = Bm + (long)(n0 + srow) * K + sseg * 8;

    for (int kk = 0; kk < K; kk += 32) {
        uint4 va = *reinterpret_cast<const uint4*>(gA + kk);
        uint4 vb = *reinterpret_cast<const uint4*>(gB + kk);
        *reinterpret_cast<uint4*>(&As[srow][sseg * 8]) = va;
        *reinterpret_cast<uint4*>(&Bs[srow][sseg * 8]) = vb;
        __syncthreads();
        bf16x8 af[2], bfr[2];
#pragma unroll
        for (int mt = 0; mt < 2; ++mt)
            af[mt] = __builtin_bit_cast(bf16x8,
                *reinterpret_cast<const uint4*>(&As[wm * 32 + mt * 16 + lm][quad * 8]));
#pragma unroll
        for (int nt = 0; nt < 2; ++nt)
            bfr[nt] = __builtin_bit_cast(bf16x8,
                *reinterpret_cast<const uint4*>(&Bs[wn * 32 + nt * 16 + lm][quad * 8]));
#pragma unroll
        for (int mt = 0; mt < 2; ++mt)
#pragma unroll
            for (int nt = 0; nt < 2; ++nt)
                acc[mt][nt] = __builtin_amdgcn_mfma_f32_16x16x32_bf16(af[mt], bfr[nt], acc[mt][nt], 0, 0, 0);
        __syncthreads();
    }
#pragma unroll
    for (int mt = 0; mt < 2; ++mt)
#pragma unroll
        for (int nt = 0; nt < 2; ++nt)
#pragma unroll
            for (int r = 0; r < 4; ++r) {
                int rg = m0 + wm * 32 + mt * 16 + quad * 4 + r;  // C/D row = quad*4+reg (verified m89/m91)
                int cg = n0 + wn * 32 + nt * 16 + lm;            // C/D col = lane&15
                float v = acc[mt][nt][r];
                if (OUT_BF16)
                    ((unsigned short*)Cm)[(long)rg * N + cg] = f2bf(v);
                else
                    ((float*)Cm)[(long)rg * N + cg] = v;
            }
}

// ---------------- fused RMSNorm + RoPE (+gain+score-scale for Q), relayout to (b,h,t,d) ----------------
// one 32-lane group per (matrix, b, t, h); lane = d
__global__ __launch_bounds__(256) void rmsnorm_rope(
    const unsigned short* __restrict__ Qraw, const unsigned short* __restrict__ Kraw,
    unsigned short* __restrict__ Qn, unsigned short* __restrict__ Kn,
    const float* __restrict__ gain, const float* __restrict__ cosp, const float* __restrict__ sinp) {
    const int tid = threadIdx.x;
    int gid = blockIdx.x * 8 + (tid >> 5);
    int lane = tid & 31;
    int mat = gid >> 17;       // 0=Q 1=K   (B*T*NH = 2^17)
    int idx = gid & 131071;    // (b*T + t)*NH + h
    int h = idx & 31;
    int bt = idx >> 5;
    int t = bt & (Tn - 1);
    int b = bt >> 11;

    const unsigned short* src = mat ? Kraw : Qraw;
    float x = bf2f(src[(long)bt * Dn + h * 32 + lane]);
    float ss = x * x;
#pragma unroll
    for (int off = 16; off >= 1; off >>= 1) ss += __shfl_xor(ss, off, 32);
    float r = rsqrtf(ss * (1.0f / 32.0f) + 1e-6f);
    float xn = x * r;
    float par = __shfl_xor(xn, 16, 32);
    float c = cosp[t * 16 + (lane & 15)];
    float s = sinp[t * 16 + (lane & 15)];
    float out = (lane < 16) ? (xn * c - par * s) : (xn * c + par * s);
    if (mat == 0) out *= gain[h] * (0.17677669529663687f * 1.4426950408889634f);  // 1/sqrt(32)*log2(e)
    unsigned short* dst = mat ? Kn : Qn;
    dst[(long)(((b * NHn + h) * Tn + t)) * 32 + lane] = f2bf(out);
}

// ---------------- V relayout: (b,t,h,d) -> Vt (b,h,d,t) via LDS tiles ----------------
__global__ __launch_bounds__(256) void v_transpose(const unsigned short* __restrict__ Vraw,
                                                   unsigned short* __restrict__ Vt) {
    const int t0 = blockIdx.x * 64, h = blockIdx.y, b = blockIdx.z;
    __shared__ unsigned short lds[32][66];
    const int tid = threadIdx.x;
#pragma unroll
    for (int rep = 0; rep < 8; ++rep) {
        int e = rep * 256 + tid;
        int d = e & 31, tt = e >> 5;
        lds[d][tt] = Vraw[(long)(b * Tn + t0 + tt) * Dn + h * 32 + d];
    }
    __syncthreads();
#pragma unroll
    for (int rep = 0; rep < 8; ++rep) {
        int e = rep * 256 + tid;
        int tt = e & 63, d = e >> 6;
        Vt[(long)((b * NHn + h) * 32 + d) * Tn + t0 + tt] = lds[d][tt];
    }
}

// ---------------- flash attention, MFMA 16x16x32, online softmax ----------------
// block = (qb 64 rows, h, b); 4 waves, wave w owns q rows q0..q0+15.
// Q prescaled by 1/sqrt(hd)*log2e*gain, so scores are already in exp2 domain.
__global__ __launch_bounds__(256) void attn(
    const unsigned short* __restrict__ Qn, const unsigned short* __restrict__ Kn,
    const unsigned short* __restrict__ Vt, unsigned short* __restrict__ Y) {
    const int qb = blockIdx.x, h = blockIdx.y, b = blockIdx.z;
    const int tid = threadIdx.x, w = tid >> 6, l = tid & 63;
    const int lm = l & 15, quad = l >> 4;
    const int q0 = qb * 64 + w * 16;
    const long bh = b * NHn + h;
    const unsigned short* Qh = Qn + bh * Tn * 32;
    const unsigned short* Kh = Kn + bh * Tn * 32;
    const unsigned short* Vh = Vt + bh * 32 * Tn;
    __shared__ __align__(16) unsigned short Pl[4][16][72];  // per-wave P tile, +8 pad

    bf16x8 qf = __builtin_bit_cast(bf16x8,
        *reinterpret_cast<const uint4*>(Qh + (q0 + lm) * 32 + quad * 8));
    f32x4 o0 = {0.f, 0.f, 0.f, 0.f}, o1 = {0.f, 0.f, 0.f, 0.f};
    float mrow[4], lrow[4];
#pragma unroll
    for (int r = 0; r < 4; ++r) { mrow[r] = -__builtin_inff(); lrow[r] = 0.f; }

    const int kend = q0 + 15;
    for (int k0 = 0; k0 <= kend; k0 += 64) {
        // S = Q K^T  (16 x 64), K stored (t,d): gemm-BT pattern
        f32x4 s[4];
#pragma unroll
        for (int i = 0; i < 4; ++i) {
            bf16x8 kf = __builtin_bit_cast(bf16x8,
                *reinterpret_cast<const uint4*>(Kh + (k0 + i * 16 + lm) * 32 + quad * 8));
            f32x4 zz = {0.f, 0.f, 0.f, 0.f};
            s[i] = __builtin_amdgcn_mfma_f32_16x16x32_bf16(qf, kf, zz, 0, 0, 0);
        }
        // causal mask + online softmax (rows of this wave live in 16-lane groups)
#pragma unroll
        for (int r = 0; r < 4; ++r) {
            int qrow = q0 + quad * 4 + r;
            float tm = -__builtin_inff();
#pragma unroll
            for (int i = 0; i < 4; ++i) {
                int kc = k0 + i * 16 + lm;
                if (kc > qrow) s[i][r] = -__builtin_inff();
                tm = fmaxf(tm, s[i][r]);
            }
#pragma unroll
            for (int off = 8; off >= 1; off >>= 1) tm = fmaxf(tm, __shfl_xor(tm, off, 16));
            float mn = fmaxf(mrow[r], tm);
            float alpha = __builtin_amdgcn_exp2f(mrow[r] - mn);
            float rs = 0.f;
#pragma unroll
            for (int i = 0; i < 4; ++i) {
                float p = __builtin_amdgcn_exp2f(s[i][r] - mn);
                s[i][r] = p;
                rs += p;
            }
#pragma unroll
            for (int off = 8; off >= 1; off >>= 1) rs += __shfl_xor(rs, off, 16);
            lrow[r] = lrow[r] * alpha + rs;
            mrow[r] = mn;
            o0[r] *= alpha;
            o1[r] *= alpha;
        }
        // P: C-layout -> LDS -> A-layout (m120-verified round trip)
#pragma unroll
        for (int i = 0; i < 4; ++i)
#pragma unroll
            for (int r = 0; r < 4; ++r)
                Pl[w][quad * 4 + r][i * 16 + lm] = f2bf(s[i][r]);
        // O += P V   (V stored (d,t): gemm-BT pattern)
#pragma unroll
        for (int kf2 = 0; kf2 < 2; ++kf2) {
            bf16x8 pf = __builtin_bit_cast(bf16x8,
                *reinterpret_cast<const uint4*>(&Pl[w][lm][kf2 * 32 + quad * 8]));
#pragma unroll
            for (int nh_ = 0; nh_ < 2; ++nh_) {
                bf16x8 vf = __builtin_bit_cast(bf16x8,
                    *reinterpret_cast<const uint4*>(Vh + (nh_ * 16 + lm) * Tn + k0 + kf2 * 32 + quad * 8));
                f32x4& oo = nh_ ? o1 : o0;
                oo = __builtin_amdgcn_mfma_f32_16x16x32_bf16(pf, vf, oo, 0, 0, 0);
            }
        }
    }
    // epilogue: divide by l, write Y in (b, t, h, d) so final GEMM reads it flat
#pragma unroll
    for (int r = 0; r < 4; ++r) {
        int qrow = q0 + quad * 4 + r;
        float inv = 1.0f / lrow[r];
        long base = ((long)(b * Tn + qrow) * NHn + h) * 32;
        Y[base + lm] = f2bf(o0[r] * inv);
        Y[base + 16 + lm] = f2bf(o1[r] * inv);
    }
}

extern "C" void kernel_launch(void* const* d_in, const int* in_sizes, int n_in,
                              void* d_out, int out_size, void* d_ws, size_t ws_size,
                              hipStream_t stream) {
    (void)in_sizes; (void)n_in; (void)out_size; (void)ws_size;
    const float* x = (const float*)d_in[0];
    const float* Wq = (const float*)d_in[1];
    const float* Wk = (const float*)d_in[2];
    const float* Wv = (const float*)d_in[3];
    const float* Wp = (const float*)d_in[4];
    const float* gain = (const float*)d_in[5];
    const float* cosp = (const float*)d_in[6];
    const float* sinp = (const float*)d_in[7];

    char* ws = (char*)d_ws;
    const size_t SZ = (size_t)Mn * Dn * 2;  // 8 MB per bf16 (4096x1024) buffer
    unsigned short* xb = (unsigned short*)ws;
    unsigned short* wqb = (unsigned short*)(ws + SZ);
    unsigned short* wkb = wqb + Dn * Dn;
    unsigned short* wvb = wkb + Dn * Dn;
    unsigned short* wpb = wvb + Dn * Dn;
    unsigned short* qraw = (unsigned short*)(ws + 2 * SZ);
    unsigned short* kraw = qraw + (size_t)Mn * Dn;
    unsigned short* vraw = kraw + (size_t)Mn * Dn;
    unsigned short* qn = vraw + (size_t)Mn * Dn;
    unsigned short* kn = qn + (size_t)Mn * Dn;
    unsigned short* vt = kn + (size_t)Mn * Dn;
    unsigned short* ybuf = vt + (size_t)Mn * Dn;
    // total ws: 9 * 8 MB = 72 MB

    cast_f32_bf16<<<4096, 256, 0, stream>>>(x, xb, Mn * Dn / 4);
    cast_f32_bf16<<<1024, 256, 0, stream>>>(Wq, wqb, Dn * Dn / 4);
    cast_f32_bf16<<<1024, 256, 0, stream>>>(Wk, wkb, Dn * Dn / 4);
    cast_f32_bf16<<<1024, 256, 0, stream>>>(Wv, wvb, Dn * Dn / 4);
    cast_f32_bf16<<<1024, 256, 0, stream>>>(Wp, wpb, Dn * Dn / 4);

    gemm_bt<true><<<dim3(Mn / 64, Dn / 64, 3), 256, 0, stream>>>(
        xb, wqb, wkb, wvb, qraw, kraw, vraw, Mn, Dn, Dn);

    rmsnorm_rope<<<32768, 256, 0, stream>>>(qraw, kraw, qn, kn, gain, cosp, sinp);
    v_transpose<<<dim3(Tn / 64, NHn, 2), 256, 0, stream>>>(vraw, vt);
    attn<<<dim3(Tn / 64, NHn, 2), 256, 0, stream>>>(qn, kn, vt, ybuf);

    gemm_bt<false><<<dim3(Mn / 64, Dn / 64, 1), 256, 0, stream>>>(
        ybuf, wpb, wpb, wpb, d_out, d_out, d_out, Mn, Dn, Dn);
}

// Round 2
// 280.666 us; speedup vs baseline: 1.3222x; 1.3222x over previous
//
#include <hip/hip_runtime.h>

#define DEV __device__ __forceinline__

typedef __bf16 bf16x8 __attribute__((ext_vector_type(8)));
typedef float f32x4 __attribute__((ext_vector_type(4)));

static constexpr int Tn = 2048;
static constexpr int Dn = 1024;
static constexpr int NHn = 32;
static constexpr int Mn = 2 * Tn;  // B*T = 4096

DEV unsigned short f2bf(float f) {
    unsigned int u = __builtin_bit_cast(unsigned int, f);
    u = u + 0x7FFFu + ((u >> 16) & 1u);
    return (unsigned short)(u >> 16);
}
DEV float bf2f(unsigned short h) {
    return __builtin_bit_cast(float, ((unsigned int)h) << 16);
}

#define GPTR(p) ((const __attribute__((address_space(1))) void*)(p))
#define LPTR(p) ((__attribute__((address_space(3))) void*)(p))

// ---------------- casts ----------------
__global__ __launch_bounds__(256) void cast_f32_bf16(const float* __restrict__ src,
                                                     unsigned short* __restrict__ dst, int n4) {
    int i = blockIdx.x * 256 + threadIdx.x;
    if (i >= n4) return;
    float4 v = reinterpret_cast<const float4*>(src)[i];
    ushort4 o;
    o.x = f2bf(v.x); o.y = f2bf(v.y); o.z = f2bf(v.z); o.w = f2bf(v.w);
    reinterpret_cast<ushort4*>(dst)[i] = o;
}

__global__ __launch_bounds__(256) void cast_w4(const float* __restrict__ s0, const float* __restrict__ s1,
                                               const float* __restrict__ s2, const float* __restrict__ s3,
                                               unsigned short* __restrict__ d0, unsigned short* __restrict__ d1,
                                               unsigned short* __restrict__ d2, unsigned short* __restrict__ d3) {
    int i = blockIdx.x * 256 + threadIdx.x;
    const float* src = (blockIdx.y == 0) ? s0 : (blockIdx.y == 1) ? s1 : (blockIdx.y == 2) ? s2 : s3;
    unsigned short* dst = (blockIdx.y == 0) ? d0 : (blockIdx.y == 1) ? d1 : (blockIdx.y == 2) ? d2 : d3;
    float4 v = reinterpret_cast<const float4*>(src)[i];
    ushort4 o;
    o.x = f2bf(v.x); o.y = f2bf(v.y); o.z = f2bf(v.z); o.w = f2bf(v.w);
    reinterpret_cast<ushort4*>(dst)[i] = o;
}

// ---------------- m97-pattern GEMM: C = A * B^T, 128x128 tile, BK=32, global_load_lds ----------------
template <bool OUT_BF16>
__global__ __launch_bounds__(256) void gemm128(
    const unsigned short* __restrict__ A,
    const unsigned short* __restrict__ B0, const unsigned short* __restrict__ B1,
    const unsigned short* __restrict__ B2,
    void* __restrict__ C0, void* __restrict__ C1, void* __restrict__ C2,
    int M, int N, int K) {
    const int z = blockIdx.z;
    const unsigned short* Bm = (z == 0) ? B0 : ((z == 1) ? B1 : B2);
    void* Cm = (z == 0) ? C0 : ((z == 1) ? C1 : C2);
    const int m0 = blockIdx.x * 128, n0 = blockIdx.y * 128;
    const int tid = threadIdx.x, w = tid >> 6, l = tid & 63;
    const int wm = w & 1, wn = w >> 1, lm = l & 15, quad = l >> 4;

    __shared__ __align__(16) unsigned short As[128 * 32];  // lane-linear: NO padding (global_load_lds)
    __shared__ __align__(16) unsigned short Bs[128 * 32];

    f32x4 acc[4][4] = {};

    // staging: wave w, parts p=0/1 cover 16 rows each; lane i -> byte offset i*16 within chunk
    const int r0 = (w * 2 + 0) * 16 + (l >> 2);
    const int r1 = (w * 2 + 1) * 16 + (l >> 2);
    const int c0 = (l & 3) * 8;
    const unsigned short* gA0 = A + (long)(m0 + r0) * K + c0;
    const unsigned short* gA1 = A + (long)(m0 + r1) * K + c0;
    const unsigned short* gB0 = Bm + (long)(n0 + r0) * K + c0;
    const unsigned short* gB1 = Bm + (long)(n0 + r1) * K + c0;
    unsigned short* lA0 = As + (w * 2 + 0) * 16 * 32;
    unsigned short* lA1 = As + (w * 2 + 1) * 16 * 32;
    unsigned short* lB0 = Bs + (w * 2 + 0) * 16 * 32;
    unsigned short* lB1 = Bs + (w * 2 + 1) * 16 * 32;

    for (int kk = 0; kk < K; kk += 32) {
        __builtin_amdgcn_global_load_lds(GPTR(gA0 + kk), LPTR(lA0), 16, 0, 0);
        __builtin_amdgcn_global_load_lds(GPTR(gA1 + kk), LPTR(lA1), 16, 0, 0);
        __builtin_amdgcn_global_load_lds(GPTR(gB0 + kk), LPTR(lB0), 16, 0, 0);
        __builtin_amdgcn_global_load_lds(GPTR(gB1 + kk), LPTR(lB1), 16, 0, 0);
        __syncthreads();  // drains vmcnt -> staged data visible
        bf16x8 af[4], bfv[4];
#pragma unroll
        for (int mt = 0; mt < 4; ++mt)
            af[mt] = __builtin_bit_cast(bf16x8,
                *reinterpret_cast<const uint4*>(As + (wm * 64 + mt * 16 + lm) * 32 + quad * 8));
#pragma unroll
        for (int nt = 0; nt < 4; ++nt)
            bfv[nt] = __builtin_bit_cast(bf16x8,
                *reinterpret_cast<const uint4*>(Bs + (wn * 64 + nt * 16 + lm) * 32 + quad * 8));
#pragma unroll
        for (int mt = 0; mt < 4; ++mt)
#pragma unroll
            for (int nt = 0; nt < 4; ++nt)
                acc[mt][nt] = __builtin_amdgcn_mfma_f32_16x16x32_bf16(af[mt], bfv[nt], acc[mt][nt], 0, 0, 0);
        __syncthreads();
    }
#pragma unroll
    for (int mt = 0; mt < 4; ++mt)
#pragma unroll
        for (int nt = 0; nt < 4; ++nt)
#pragma unroll
            for (int r = 0; r < 4; ++r) {
                int rg = m0 + wm * 64 + mt * 16 + quad * 4 + r;  // C/D row = quad*4+reg
                int cg = n0 + wn * 64 + nt * 16 + lm;            // C/D col = lane&15
                float v = acc[mt][nt][r];
                if (OUT_BF16)
                    ((unsigned short*)Cm)[(long)rg * N + cg] = f2bf(v);
                else
                    ((float*)Cm)[(long)rg * N + cg] = v;
            }
}

// ---------------- fused RMSNorm + RoPE, relayout to (b,h,t,d) ----------------
__global__ __launch_bounds__(256) void rmsnorm_rope(
    const unsigned short* __restrict__ Qraw, const unsigned short* __restrict__ Kraw,
    unsigned short* __restrict__ Qn, unsigned short* __restrict__ Kn,
    const float* __restrict__ gain, const float* __restrict__ cosp, const float* __restrict__ sinp) {
    const int tid = threadIdx.x;
    int gid = blockIdx.x * 8 + (tid >> 5);
    int lane = tid & 31;
    int mat = gid >> 17;
    int idx = gid & 131071;
    int h = idx & 31;
    int bt = idx >> 5;
    int t = bt & (Tn - 1);
    int b = bt >> 11;

    const unsigned short* src = mat ? Kraw : Qraw;
    float x = bf2f(src[(long)bt * Dn + h * 32 + lane]);
    float ss = x * x;
#pragma unroll
    for (int off = 16; off >= 1; off >>= 1) ss += __shfl_xor(ss, off, 32);
    float r = rsqrtf(ss * (1.0f / 32.0f) + 1e-6f);
    float xn = x * r;
    float par = __shfl_xor(xn, 16, 32);
    float c = cosp[t * 16 + (lane & 15)];
    float s = sinp[t * 16 + (lane & 15)];
    float out = (lane < 16) ? (xn * c - par * s) : (xn * c + par * s);
    if (mat == 0) out *= gain[h] * (0.17677669529663687f * 1.4426950408889634f);  // 1/sqrt(32)*log2(e)
    unsigned short* dst = mat ? Kn : Qn;
    dst[(long)(((b * NHn + h) * Tn + t)) * 32 + lane] = f2bf(out);
}

// ---------------- V transpose: (b,t,h,d) -> (b,h,d,t) ----------------
__global__ __launch_bounds__(256) void v_transpose(const unsigned short* __restrict__ Vraw,
                                                   unsigned short* __restrict__ Vt) {
    const int t0 = blockIdx.x * 64, h = blockIdx.y, b = blockIdx.z;
    __shared__ unsigned short lds[32][66];
    const int tid = threadIdx.x;
#pragma unroll
    for (int rep = 0; rep < 8; ++rep) {
        int e = rep * 256 + tid;
        int d = e & 31, tt = e >> 5;
        lds[d][tt] = Vraw[(long)(b * Tn + t0 + tt) * Dn + h * 32 + d];
    }
    __syncthreads();
#pragma unroll
    for (int rep = 0; rep < 8; ++rep) {
        int e = rep * 256 + tid;
        int tt = e & 63, d = e >> 6;
        Vt[(long)((b * NHn + h) * 32 + d) * Tn + t0 + tt] = lds[d][tt];
    }
}

// ---------------- flash attention: static per-row softmax bound, deferred l-reduction ----------------
// block = 256 thr = 4 waves; wave w owns 32 q rows (2 MFMA frags). Q prescaled to exp2 domain.
// |k_row| <= sqrt(32) exactly (rmsnorm), so M_row = |q_row|*sqrt(32) bounds all scores -> no running max.
__global__ __launch_bounds__(256) void attn(
    const unsigned short* __restrict__ Qn, const unsigned short* __restrict__ Kn,
    const unsigned short* __restrict__ Vt, unsigned short* __restrict__ Y) {
    const int qb = blockIdx.x, h = blockIdx.y, b = blockIdx.z;
    const int tid = threadIdx.x, w = tid >> 6, l = tid & 63;
    const int lm = l & 15, quad = l >> 4;
    const int q0 = qb * 128 + w * 32;
    const long bh = b * NHn + h;
    const unsigned short* Qh = Qn + bh * Tn * 32;
    const unsigned short* Kh = Kn + bh * Tn * 32;
    const unsigned short* Vh = Vt + bh * 32 * Tn;
    __shared__ __align__(16) unsigned short Pl[4][16][72];
    unsigned short* Pw = &Pl[w][0][0];

    bf16x8 qf[2];
    float negM[2][4];
    float lpart[2][4] = {};
    f32x4 o[2][2] = {{{0.f, 0.f, 0.f, 0.f}, {0.f, 0.f, 0.f, 0.f}},
                     {{0.f, 0.f, 0.f, 0.f}, {0.f, 0.f, 0.f, 0.f}}};
#pragma unroll
    for (int t = 0; t < 2; ++t) {
        qf[t] = __builtin_bit_cast(bf16x8,
            *reinterpret_cast<const uint4*>(Qh + (q0 + t * 16 + lm) * 32 + quad * 8));
        float ss = 0.f;
#pragma unroll
        for (int j = 0; j < 8; ++j) { float v = (float)qf[t][j]; ss += v * v; }
        ss += __shfl_xor(ss, 16);
        ss += __shfl_xor(ss, 32);
        float Mv = __builtin_sqrtf(ss * 32.0f);  // exact bound: |q_row| * |k_row|max
#pragma unroll
        for (int r = 0; r < 4; ++r) negM[t][r] = -__shfl(Mv, quad * 4 + r, 16);
    }

    const int kend = q0 + 31;
    for (int k0 = 0; k0 <= kend; k0 += 64) {
        bf16x8 kf[4], vf[4];
#pragma unroll
        for (int i = 0; i < 4; ++i)
            kf[i] = __builtin_bit_cast(bf16x8,
                *reinterpret_cast<const uint4*>(Kh + (k0 + i * 16 + lm) * 32 + quad * 8));
#pragma unroll
        for (int kf2 = 0; kf2 < 2; ++kf2)
#pragma unroll
            for (int nh_ = 0; nh_ < 2; ++nh_)
                vf[kf2 * 2 + nh_] = __builtin_bit_cast(bf16x8,
                    *reinterpret_cast<const uint4*>(Vh + (nh_ * 16 + lm) * Tn + k0 + kf2 * 32 + quad * 8));
#pragma unroll
        for (int t = 0; t < 2; ++t) {
            if (k0 > q0 + t * 16 + 15) continue;  // tile entirely beyond this frag's rows
            f32x4 s[4];
#pragma unroll
            for (int i = 0; i < 4; ++i) {
                f32x4 zz = {0.f, 0.f, 0.f, 0.f};
                s[i] = __builtin_amdgcn_mfma_f32_16x16x32_bf16(qf[t], kf[i], zz, 0, 0, 0);
            }
            const bool full = (k0 + 63) <= (q0 + t * 16);  // no masking needed
#pragma unroll
            for (int r = 0; r < 4; ++r) {
                const int qrow = q0 + t * 16 + quad * 4 + r;
                const float nm = negM[t][r];
                float ls = lpart[t][r];
#pragma unroll
                for (int i = 0; i < 4; ++i) {
                    float p = __builtin_amdgcn_exp2f(s[i][r] + nm);
                    if (!full) {
                        int kc = k0 + i * 16 + lm;
                        p = (kc <= qrow) ? p : 0.0f;
                    }
                    s[i][r] = p;
                    ls += p;
                }
                lpart[t][r] = ls;
            }
            // P: C-layout -> LDS -> A-layout (per-wave buffer, no barrier needed)
#pragma unroll
            for (int i = 0; i < 4; ++i)
#pragma unroll
                for (int r = 0; r < 4; ++r)
                    Pw[(quad * 4 + r) * 72 + i * 16 + lm] = f2bf(s[i][r]);
#pragma unroll
            for (int kf2 = 0; kf2 < 2; ++kf2) {
                bf16x8 pf = __builtin_bit_cast(bf16x8,
                    *reinterpret_cast<const uint4*>(Pw + lm * 72 + kf2 * 32 + quad * 8));
#pragma unroll
                for (int nh_ = 0; nh_ < 2; ++nh_)
                    o[t][nh_] = __builtin_amdgcn_mfma_f32_16x16x32_bf16(pf, vf[kf2 * 2 + nh_], o[t][nh_], 0, 0, 0);
            }
        }
    }
#pragma unroll
    for (int t = 0; t < 2; ++t)
#pragma unroll
        for (int r = 0; r < 4; ++r) {
            float ls = lpart[t][r];
#pragma unroll
            for (int off = 8; off >= 1; off >>= 1) ls += __shfl_xor(ls, off, 16);
            float inv = 1.0f / ls;
            int qrow = q0 + t * 16 + quad * 4 + r;
            long base = ((long)(b * Tn + qrow) * NHn + h) * 32;
            Y[base + lm] = f2bf(o[t][0][r] * inv);
            Y[base + 16 + lm] = f2bf(o[t][1][r] * inv);
        }
}

extern "C" void kernel_launch(void* const* d_in, const int* in_sizes, int n_in,
                              void* d_out, int out_size, void* d_ws, size_t ws_size,
                              hipStream_t stream) {
    (void)in_sizes; (void)n_in; (void)out_size; (void)ws_size;
    const float* x = (const float*)d_in[0];
    const float* Wq = (const float*)d_in[1];
    const float* Wk = (const float*)d_in[2];
    const float* Wv = (const float*)d_in[3];
    const float* Wp = (const float*)d_in[4];
    const float* gain = (const float*)d_in[5];
    const float* cosp = (const float*)d_in[6];
    const float* sinp = (const float*)d_in[7];

    char* ws = (char*)d_ws;
    const size_t SZ = (size_t)Mn * Dn * 2;  // 8 MB
    unsigned short* xb = (unsigned short*)ws;
    unsigned short* wqb = (unsigned short*)(ws + SZ);
    unsigned short* wkb = wqb + Dn * Dn;
    unsigned short* wvb = wkb + Dn * Dn;
    unsigned short* wpb = wvb + Dn * Dn;
    unsigned short* qraw = (unsigned short*)(ws + 2 * SZ);
    unsigned short* kraw = qraw + (size_t)Mn * Dn;
    unsigned short* vraw = kraw + (size_t)Mn * Dn;
    unsigned short* qn = vraw + (size_t)Mn * Dn;
    unsigned short* kn = qn + (size_t)Mn * Dn;
    unsigned short* vt = kn + (size_t)Mn * Dn;
    unsigned short* ybuf = vt + (size_t)Mn * Dn;

    cast_f32_bf16<<<4096, 256, 0, stream>>>(x, xb, Mn * Dn / 4);
    cast_w4<<<dim3(1024, 4), 256, 0, stream>>>(Wq, Wk, Wv, Wp, wqb, wkb, wvb, wpb);

    gemm128<true><<<dim3(Mn / 128, Dn / 128, 3), 256, 0, stream>>>(
        xb, wqb, wkb, wvb, qraw, kraw, vraw, Mn, Dn, Dn);

    rmsnorm_rope<<<32768, 256, 0, stream>>>(qraw, kraw, qn, kn, gain, cosp, sinp);
    v_transpose<<<dim3(Tn / 64, NHn, 2), 256, 0, stream>>>(vraw, vt);
    attn<<<dim3(Tn / 128, NHn, 2), 256, 0, stream>>>(qn, kn, vt, ybuf);

    gemm128<false><<<dim3(Mn / 128, Dn / 128, 1), 256, 0, stream>>>(
        ybuf, wpb, wpb, wpb, d_out, d_out, d_out, Mn, Dn, Dn);
}

// Round 3
// 213.733 us; speedup vs baseline: 1.7362x; 1.3132x over previous
//
#include <hip/hip_runtime.h>

#define DEV __device__ __forceinline__

typedef __bf16 bf16x8 __attribute__((ext_vector_type(8)));
typedef float f32x4 __attribute__((ext_vector_type(4)));

static constexpr int Tn = 2048;
static constexpr int Dn = 1024;
static constexpr int NHn = 32;
static constexpr int Mn = 2 * Tn;  // B*T = 4096
static constexpr float QSCALE = 0.17677669529663687f * 1.4426950408889634f;  // 1/sqrt(32)*log2e

DEV unsigned short f2bf(float f) {
    unsigned int u = __builtin_bit_cast(unsigned int, f);
    u = u + 0x7FFFu + ((u >> 16) & 1u);
    return (unsigned short)(u >> 16);
}

#define GPTR(p) ((const __attribute__((address_space(1))) void*)(p))
#define LPTR(p) ((__attribute__((address_space(3))) void*)(p))

// ---------------- single fused cast: x (1M float4) + 4 weights (1M float4) ----------------
__global__ __launch_bounds__(256) void cast_all(
    const float* __restrict__ x, const float* __restrict__ Wq, const float* __restrict__ Wk,
    const float* __restrict__ Wv, const float* __restrict__ Wp,
    unsigned short* __restrict__ xb, unsigned short* __restrict__ wall) {
    int i = blockIdx.x * 256 + threadIdx.x;  // [0, 2M)
    const float* src;
    ushort4* dst;
    if (i < (1 << 20)) {
        src = x + (size_t)i * 4;
        dst = reinterpret_cast<ushort4*>(xb) + i;
    } else {
        int j = i - (1 << 20);
        int sel = j >> 18, off = j & ((1 << 18) - 1);
        const float* w = (sel == 0) ? Wq : (sel == 1) ? Wk : (sel == 2) ? Wv : Wp;
        src = w + (size_t)off * 4;
        dst = reinterpret_cast<ushort4*>(wall) + ((size_t)sel << 18) + off;
    }
    float4 v = *reinterpret_cast<const float4*>(src);
    ushort4 o;
    o.x = f2bf(v.x); o.y = f2bf(v.y); o.z = f2bf(v.z); o.w = f2bf(v.w);
    *dst = o;
}

// ---------------- fused QKV GEMM (m97 pattern) + RMSNorm/RoPE/relayout epilogue ----------------
// z=0: Q -> rms+rope+gain+exp2-scale -> Qn (b,h,t,d)
// z=1: K -> rms+rope              -> Kn (b,h,t,d)
// z=2: V -> transpose store        -> Vt (b,h,d,t)
__global__ __launch_bounds__(256) void gemm_qkv(
    const unsigned short* __restrict__ A, const unsigned short* __restrict__ Wall,
    unsigned short* __restrict__ Qn, unsigned short* __restrict__ Kn, unsigned short* __restrict__ Vt,
    const float* __restrict__ gain, const float* __restrict__ cosp, const float* __restrict__ sinp) {
    const int z = blockIdx.z;
    const unsigned short* Bm = Wall + (size_t)z * (Dn * Dn);
    const int m0 = blockIdx.x * 128, n0 = blockIdx.y * 128;
    const int tid = threadIdx.x, w = tid >> 6, l = tid & 63;
    const int wm = w & 1, wn = w >> 1, lm = l & 15, quad = l >> 4;

    __shared__ __align__(16) unsigned short As[128 * 32];  // lane-linear, no padding (global_load_lds)
    __shared__ __align__(16) unsigned short Bs[128 * 32];

    f32x4 acc[4][4] = {};

    const int r0 = (w * 2 + 0) * 16 + (l >> 2);
    const int r1 = (w * 2 + 1) * 16 + (l >> 2);
    const int c0 = (l & 3) * 8;
    const unsigned short* gA0 = A + (long)(m0 + r0) * Dn + c0;
    const unsigned short* gA1 = A + (long)(m0 + r1) * Dn + c0;
    const unsigned short* gB0 = Bm + (long)(n0 + r0) * Dn + c0;
    const unsigned short* gB1 = Bm + (long)(n0 + r1) * Dn + c0;
    unsigned short* lA0 = As + (w * 2 + 0) * 16 * 32;
    unsigned short* lA1 = As + (w * 2 + 1) * 16 * 32;
    unsigned short* lB0 = Bs + (w * 2 + 0) * 16 * 32;
    unsigned short* lB1 = Bs + (w * 2 + 1) * 16 * 32;

    for (int kk = 0; kk < Dn; kk += 32) {
        __builtin_amdgcn_global_load_lds(GPTR(gA0 + kk), LPTR(lA0), 16, 0, 0);
        __builtin_amdgcn_global_load_lds(GPTR(gA1 + kk), LPTR(lA1), 16, 0, 0);
        __builtin_amdgcn_global_load_lds(GPTR(gB0 + kk), LPTR(lB0), 16, 0, 0);
        __builtin_amdgcn_global_load_lds(GPTR(gB1 + kk), LPTR(lB1), 16, 0, 0);
        __syncthreads();
        bf16x8 af[4], bfv[4];
#pragma unroll
        for (int mt = 0; mt < 4; ++mt)
            af[mt] = __builtin_bit_cast(bf16x8,
                *reinterpret_cast<const uint4*>(As + (wm * 64 + mt * 16 + lm) * 32 + quad * 8));
#pragma unroll
        for (int nt = 0; nt < 4; ++nt)
            bfv[nt] = __builtin_bit_cast(bf16x8,
                *reinterpret_cast<const uint4*>(Bs + (wn * 64 + nt * 16 + lm) * 32 + quad * 8));
#pragma unroll
        for (int mt = 0; mt < 4; ++mt)
#pragma unroll
            for (int nt = 0; nt < 4; ++nt)
                acc[mt][nt] = __builtin_amdgcn_mfma_f32_16x16x32_bf16(af[mt], bfv[nt], acc[mt][nt], 0, 0, 0);
        __syncthreads();
    }

    if (z == 2) {
        // V transpose-store: rows r=0..3 are consecutive t -> ushort4
#pragma unroll
        for (int mt = 0; mt < 4; ++mt) {
            int row0 = m0 + wm * 64 + mt * 16 + quad * 4;
            int b_ = row0 >> 11, t_ = row0 & (Tn - 1);
#pragma unroll
            for (int nt = 0; nt < 4; ++nt) {
                int col = n0 + wn * 64 + nt * 16 + lm;
                int hh = col >> 5, dd = col & 31;
                ushort4 o4;
                o4.x = f2bf(acc[mt][nt][0]); o4.y = f2bf(acc[mt][nt][1]);
                o4.z = f2bf(acc[mt][nt][2]); o4.w = f2bf(acc[mt][nt][3]);
                *reinterpret_cast<ushort4*>(&Vt[((long)(b_ * NHn + hh) * 32 + dd) * Tn + t_]) = o4;
            }
        }
    } else {
        unsigned short* dst = z ? Kn : Qn;
#pragma unroll
        for (int mt = 0; mt < 4; ++mt)
#pragma unroll
            for (int r = 0; r < 4; ++r) {
                int row = m0 + wm * 64 + mt * 16 + quad * 4 + r;
                int b_ = row >> 11, t_ = row & (Tn - 1);
                float c = cosp[t_ * 16 + lm], s = sinp[t_ * 16 + lm];
#pragma unroll
                for (int g = 0; g < 2; ++g) {
                    // head = 32 cols = nt in {2g, 2g+1}; RoPE pair (d, d+16) lives in same lane
                    float x1 = acc[mt][2 * g][r], x2 = acc[mt][2 * g + 1][r];
                    float ssv = x1 * x1 + x2 * x2;
#pragma unroll
                    for (int off = 8; off >= 1; off >>= 1) ssv += __shfl_xor(ssv, off, 16);
                    float rinv = rsqrtf(ssv * (1.0f / 32.0f) + 1e-6f);
                    x1 *= rinv; x2 *= rinv;
                    float o1 = x1 * c - x2 * s;
                    float o2 = x2 * c + x1 * s;
                    int hh = (n0 + wn * 64 + g * 32) >> 5;
                    if (z == 0) { float gs = gain[hh] * QSCALE; o1 *= gs; o2 *= gs; }
                    long base = ((long)(b_ * NHn + hh) * Tn + t_) * 32;
                    dst[base + lm] = f2bf(o1);
                    dst[base + 16 + lm] = f2bf(o2);
                }
            }
    }
}

// ---------------- proj GEMM (m97 pattern), fp32 out ----------------
__global__ __launch_bounds__(256) void gemm_proj(
    const unsigned short* __restrict__ A, const unsigned short* __restrict__ Bm,
    float* __restrict__ C) {
    const int m0 = blockIdx.x * 128, n0 = blockIdx.y * 128;
    const int tid = threadIdx.x, w = tid >> 6, l = tid & 63;
    const int wm = w & 1, wn = w >> 1, lm = l & 15, quad = l >> 4;

    __shared__ __align__(16) unsigned short As[128 * 32];
    __shared__ __align__(16) unsigned short Bs[128 * 32];

    f32x4 acc[4][4] = {};

    const int r0 = (w * 2 + 0) * 16 + (l >> 2);
    const int r1 = (w * 2 + 1) * 16 + (l >> 2);
    const int c0 = (l & 3) * 8;
    const unsigned short* gA0 = A + (long)(m0 + r0) * Dn + c0;
    const unsigned short* gA1 = A + (long)(m0 + r1) * Dn + c0;
    const unsigned short* gB0 = Bm + (long)(n0 + r0) * Dn + c0;
    const unsigned short* gB1 = Bm + (long)(n0 + r1) * Dn + c0;
    unsigned short* lA0 = As + (w * 2 + 0) * 16 * 32;
    unsigned short* lA1 = As + (w * 2 + 1) * 16 * 32;
    unsigned short* lB0 = Bs + (w * 2 + 0) * 16 * 32;
    unsigned short* lB1 = Bs + (w * 2 + 1) * 16 * 32;

    for (int kk = 0; kk < Dn; kk += 32) {
        __builtin_amdgcn_global_load_lds(GPTR(gA0 + kk), LPTR(lA0), 16, 0, 0);
        __builtin_amdgcn_global_load_lds(GPTR(gA1 + kk), LPTR(lA1), 16, 0, 0);
        __builtin_amdgcn_global_load_lds(GPTR(gB0 + kk), LPTR(lB0), 16, 0, 0);
        __builtin_amdgcn_global_load_lds(GPTR(gB1 + kk), LPTR(lB1), 16, 0, 0);
        __syncthreads();
        bf16x8 af[4], bfv[4];
#pragma unroll
        for (int mt = 0; mt < 4; ++mt)
            af[mt] = __builtin_bit_cast(bf16x8,
                *reinterpret_cast<const uint4*>(As + (wm * 64 + mt * 16 + lm) * 32 + quad * 8));
#pragma unroll
        for (int nt = 0; nt < 4; ++nt)
            bfv[nt] = __builtin_bit_cast(bf16x8,
                *reinterpret_cast<const uint4*>(Bs + (wn * 64 + nt * 16 + lm) * 32 + quad * 8));
#pragma unroll
        for (int mt = 0; mt < 4; ++mt)
#pragma unroll
            for (int nt = 0; nt < 4; ++nt)
                acc[mt][nt] = __builtin_amdgcn_mfma_f32_16x16x32_bf16(af[mt], bfv[nt], acc[mt][nt], 0, 0, 0);
        __syncthreads();
    }
#pragma unroll
    for (int mt = 0; mt < 4; ++mt)
#pragma unroll
        for (int nt = 0; nt < 4; ++nt)
#pragma unroll
            for (int r = 0; r < 4; ++r) {
                int rg = m0 + wm * 64 + mt * 16 + quad * 4 + r;
                int cg = n0 + wn * 64 + nt * 16 + lm;
                C[(long)rg * Dn + cg] = acc[mt][nt][r];
            }
}

// ---------------- flash attention: paired q-tiles (balance) + K/V register prefetch ----------------
// block bx handles qb = bx and qb = 15-bx -> every block does ~34 k-tiles. 4 waves, wave w owns
// 32 q rows (2 frags). Q prescaled to exp2 domain; static per-row bound M = |q||k|max (rms -> |k|<=sqrt(32)).
__global__ __launch_bounds__(256) void attn(
    const unsigned short* __restrict__ Qn, const unsigned short* __restrict__ Kn,
    const unsigned short* __restrict__ Vt, unsigned short* __restrict__ Y) {
    const int bx = blockIdx.x, h = blockIdx.y, b = blockIdx.z;
    const int tid = threadIdx.x, w = tid >> 6, l = tid & 63;
    const int lm = l & 15, quad = l >> 4;
    const long bh = b * NHn + h;
    const unsigned short* Qh = Qn + bh * Tn * 32;
    const unsigned short* Kh = Kn + bh * Tn * 32;
    const unsigned short* Vh = Vt + bh * 32 * Tn;
    __shared__ __align__(16) unsigned short Pl[4][16][76];  // stride 76: quads land on disjoint banks
    unsigned short* Pw = &Pl[w][0][0];

    for (int pass = 0; pass < 2; ++pass) {
        const int qb = pass ? (15 - bx) : bx;
        const int q0 = qb * 128 + w * 32;

        bf16x8 qf[2];
        float negM[2][4];
        float lpart[2][4] = {};
        f32x4 o[2][2] = {{{0.f, 0.f, 0.f, 0.f}, {0.f, 0.f, 0.f, 0.f}},
                         {{0.f, 0.f, 0.f, 0.f}, {0.f, 0.f, 0.f, 0.f}}};
#pragma unroll
        for (int t = 0; t < 2; ++t) {
            qf[t] = __builtin_bit_cast(bf16x8,
                *reinterpret_cast<const uint4*>(Qh + (q0 + t * 16 + lm) * 32 + quad * 8));
            float ss = 0.f;
#pragma unroll
            for (int j = 0; j < 8; ++j) { float v = (float)qf[t][j]; ss += v * v; }
            ss += __shfl_xor(ss, 16);
            ss += __shfl_xor(ss, 32);
            float Mv = __builtin_sqrtf(ss * 32.0f);
#pragma unroll
            for (int r = 0; r < 4; ++r) negM[t][r] = -__shfl(Mv, quad * 4 + r, 16);
        }

        const int kend = q0 + 31;
        uint4 ka[4], va[4], kb2[4], vb2[4];

        auto load_t = [&](uint4* kd, uint4* vd, int k0) {
#pragma unroll
            for (int i = 0; i < 4; ++i)
                kd[i] = *reinterpret_cast<const uint4*>(Kh + (k0 + i * 16 + lm) * 32 + quad * 8);
#pragma unroll
            for (int kf2 = 0; kf2 < 2; ++kf2)
#pragma unroll
                for (int nh_ = 0; nh_ < 2; ++nh_)
                    vd[kf2 * 2 + nh_] = *reinterpret_cast<const uint4*>(
                        Vh + (nh_ * 16 + lm) * Tn + k0 + kf2 * 32 + quad * 8);
        };

        auto compute_t = [&](const uint4* kd, const uint4* vd, int k0) {
#pragma unroll
            for (int t = 0; t < 2; ++t) {
                if (k0 > q0 + t * 16 + 15) continue;
                f32x4 s[4];
#pragma unroll
                for (int i = 0; i < 4; ++i) {
                    f32x4 zz = {0.f, 0.f, 0.f, 0.f};
                    s[i] = __builtin_amdgcn_mfma_f32_16x16x32_bf16(
                        qf[t], __builtin_bit_cast(bf16x8, kd[i]), zz, 0, 0, 0);
                }
                const bool full = (k0 + 63) <= (q0 + t * 16);
#pragma unroll
                for (int r = 0; r < 4; ++r) {
                    const int qrow = q0 + t * 16 + quad * 4 + r;
                    const float nm = negM[t][r];
                    float ls = lpart[t][r];
#pragma unroll
                    for (int i = 0; i < 4; ++i) {
                        float p = __builtin_amdgcn_exp2f(s[i][r] + nm);
                        if (!full) {
                            int kc = k0 + i * 16 + lm;
                            p = (kc <= qrow) ? p : 0.0f;
                        }
                        s[i][r] = p;
                        ls += p;
                    }
                    lpart[t][r] = ls;
                }
#pragma unroll
                for (int i = 0; i < 4; ++i)
#pragma unroll
                    for (int r = 0; r < 4; ++r)
                        Pw[(quad * 4 + r) * 76 + i * 16 + lm] = f2bf(s[i][r]);
#pragma unroll
                for (int kf2 = 0; kf2 < 2; ++kf2) {
                    bf16x8 pf = __builtin_bit_cast(bf16x8,
                        *reinterpret_cast<const uint4*>(Pw + lm * 76 + kf2 * 32 + quad * 8));
#pragma unroll
                    for (int nh_ = 0; nh_ < 2; ++nh_)
                        o[t][nh_] = __builtin_amdgcn_mfma_f32_16x16x32_bf16(
                            pf, __builtin_bit_cast(bf16x8, vd[kf2 * 2 + nh_]), o[t][nh_], 0, 0, 0);
                }
            }
        };

        // ping-pong: prefetch next tile's K/V while computing current
        load_t(ka, va, 0);
        int k0 = 0;
        while (true) {
            int nk = k0 + 64;
            if (nk <= kend) load_t(kb2, vb2, nk);
            compute_t(ka, va, k0);
            if (nk > kend) break;
            k0 = nk;
            nk = k0 + 64;
            if (nk <= kend) load_t(ka, va, nk);
            compute_t(kb2, vb2, k0);
            if (nk > kend) break;
            k0 = nk;
        }

#pragma unroll
        for (int t = 0; t < 2; ++t)
#pragma unroll
            for (int r = 0; r < 4; ++r) {
                float ls = lpart[t][r];
#pragma unroll
                for (int off = 8; off >= 1; off >>= 1) ls += __shfl_xor(ls, off, 16);
                float inv = 1.0f / ls;
                int qrow = q0 + t * 16 + quad * 4 + r;
                long base = ((long)(b * Tn + qrow) * NHn + h) * 32;
                Y[base + lm] = f2bf(o[t][0][r] * inv);
                Y[base + 16 + lm] = f2bf(o[t][1][r] * inv);
            }
    }
}

extern "C" void kernel_launch(void* const* d_in, const int* in_sizes, int n_in,
                              void* d_out, int out_size, void* d_ws, size_t ws_size,
                              hipStream_t stream) {
    (void)in_sizes; (void)n_in; (void)out_size; (void)ws_size;
    const float* x = (const float*)d_in[0];
    const float* Wq = (const float*)d_in[1];
    const float* Wk = (const float*)d_in[2];
    const float* Wv = (const float*)d_in[3];
    const float* Wp = (const float*)d_in[4];
    const float* gain = (const float*)d_in[5];
    const float* cosp = (const float*)d_in[6];
    const float* sinp = (const float*)d_in[7];

    char* ws = (char*)d_ws;
    const size_t SZ = (size_t)Mn * Dn * 2;  // 8 MB
    unsigned short* xb = (unsigned short*)ws;
    unsigned short* wall = (unsigned short*)(ws + SZ);  // [Wq|Wk|Wv|Wp], 8 MB
    unsigned short* qn = (unsigned short*)(ws + 2 * SZ);
    unsigned short* kn = qn + (size_t)Mn * Dn;
    unsigned short* vt = kn + (size_t)Mn * Dn;
    unsigned short* ybuf = vt + (size_t)Mn * Dn;
    // total ws: 48 MB

    cast_all<<<8192, 256, 0, stream>>>(x, Wq, Wk, Wv, Wp, xb, wall);

    gemm_qkv<<<dim3(Mn / 128, Dn / 128, 3), 256, 0, stream>>>(
        xb, wall, qn, kn, vt, gain, cosp, sinp);

    attn<<<dim3(8, NHn, 2), 256, 0, stream>>>(qn, kn, vt, ybuf);

    gemm_proj<<<dim3(Mn / 128, Dn / 128), 256, 0, stream>>>(
        ybuf, wall + (size_t)3 * Dn * Dn, (float*)d_out);
}